// Round 11
// baseline (101.880 us; speedup 1.0000x reference)
//
#include <hip/hip_runtime.h>
#include <hip/hip_bf16.h>

#define ROWS 1025   // B*N + 1
#define DD   128    // D
#define C3   384    // 3*D
#define BB   8
#define NN   128

#define NL2E  (-1.4426950408889634f)   // -log2(e)

__device__ __forceinline__ unsigned short f2bf(float f) {
    unsigned int i = __float_as_uint(f);            // finite data only
    return (unsigned short)((i + 0x7FFFu + ((i >> 16) & 1u)) >> 16);
}

// Transpose + pre-scale the 4 weight matrices [384][128] -> [128][384]:
//   WT[k][cc] = W[cc][k] * (cc>=256 ? 2*NL2E : NL2E)
__global__ __launch_bounds__(256) void wprep_kernel(
    const float* __restrict__ Wib, const float* __restrict__ Whb,
    const float* __restrict__ Wif, const float* __restrict__ Whf,
    float* __restrict__ WT) {            // 4 contiguous [128][384] tables
    const int mat = blockIdx.x / 48, tile = blockIdx.x % 48;
    const int tr = tile / 4, tc = tile % 4;      // row-tile (cc), col-tile (k)
    const float* __restrict__ src = (mat == 0) ? Wib : (mat == 1) ? Whb
                                   : (mat == 2) ? Wif : Whf;
    float* __restrict__ dst = WT + (size_t)mat * DD * C3;
    __shared__ float tl[32][33];
    const int tx = threadIdx.x & 31, ty = threadIdx.x >> 5;   // 8 rows/pass
#pragma unroll
    for (int p = 0; p < 32; p += 8) {
        const int cc = tr * 32 + ty + p, k = tc * 32 + tx;
        const float sc = (cc >= 256) ? 2.0f * NL2E : NL2E;
        tl[ty + p][tx] = src[(size_t)cc * DD + k] * sc;
    }
    __syncthreads();
#pragma unroll
    for (int p = 0; p < 32; p += 8) {
        const int k = tc * 32 + ty + p, cc = tr * 32 + tx;
        dst[(size_t)k * C3 + cc] = tl[tx][ty + p];
    }
}

// Pre-scaled packed gate tables, bf16x4 per (row, d):  [R9 verbatim]
//   GiP[row][d] = {-L*ir, -L*iz, -2L*in, (unused)}
//   GhP[row][d] = {-L*hr, -L*hz, -2L*hn, h}
__global__ __launch_bounds__(768) void gtab_kernel(
    const float* __restrict__ h,
    const float* __restrict__ WiT, const float* __restrict__ WhT,
    const float* __restrict__ bi, const float* __restrict__ bh,
    unsigned short* __restrict__ GiP, unsigned short* __restrict__ GhP) {
    __shared__ float hsT[DD][4];        // 2 KB
    const int t  = threadIdx.x;
    const int r0 = blockIdx.x * 4;
    if (t < 512) {
        const int r = t & 3, k = t >> 2;
        const int row = r0 + r;
        hsT[k][r] = (row < ROWS) ? h[(size_t)row * DD + k] : 0.0f;
    }
    __syncthreads();

    const bool isI  = t < C3;
    const int  cc   = isI ? t : t - C3;
    const int  gate = cc >> 7, d = cc & (DD - 1);
    const float* __restrict__ WT = isI ? WiT : WhT;
    const float scale = (gate == 2) ? 2.0f * NL2E : NL2E;
    const float bs = (isI ? bi : bh)[cc] * scale;   // weights pre-scaled in WT

    float a0 = 0.f, a1 = 0.f, a2 = 0.f, a3 = 0.f;
#pragma unroll 8
    for (int k = 0; k < DD; ++k) {
        const float  w  = WT[(size_t)k * C3 + cc];
        const float4 hv = *reinterpret_cast<const float4*>(&hsT[k][0]);
        a0 += w * hv.x; a1 += w * hv.y; a2 += w * hv.z; a3 += w * hv.w;
    }

    unsigned short* __restrict__ G = isI ? GiP : GhP;
    const float av[4] = {a0, a1, a2, a3};
#pragma unroll
    for (int r = 0; r < 4; ++r) {
        const int row = r0 + r;
        if (row < ROWS) G[(size_t)row * 512 + d * 4 + gate] = f2bf(av[r] + bs);
    }
    if (!isI && gate == 0) {            // h-value slot (GhP .w)
#pragma unroll
        for (int r = 0; r < 4; ++r) {
            const int row = r0 + r;
            if (row < ROWS) GhP[(size_t)row * 512 + d * 4 + 3] = f2bf(hsT[d][r]);
        }
    }
}

// One block per (b,j); 512 threads = (ic 0..3) x (d 0..127).  [R9 verbatim]
template<int XC, int WRITE_OUT>
__global__ __launch_bounds__(512, 4) void phase_kernel(
    const float* __restrict__ hin,
    const int* __restrict__ parent, const int* __restrict__ child,
    const unsigned short* __restrict__ GiP, const unsigned short* __restrict__ GhP,
    float* __restrict__ hout,
    const int* __restrict__ tgt, float* __restrict__ out) {
    const int bj = blockIdx.x;          // 0..1023
    const int t  = threadIdx.x;
    const int b  = bj >> 7, j = bj & (NN - 1);
    const size_t base = (size_t)b * NN * NN + j;          // + i*NN

    __shared__ int   pcs[2 * NN];       // interleaved {p,c} pairs
    __shared__ float sacc[4][DD];
    if (t < NN)            pcs[2 * t]            = parent[base + (size_t)t * NN];
    else if (t < 2 * NN)   pcs[2 * (t - NN) + 1] = child [base + (size_t)(t - NN) * NN];
    __syncthreads();

    const int ic = t >> 7, d = t & (DD - 1);
    float acc = 0.0f;
#pragma unroll 4
    for (int k = 0; k < 32; ++k) {
        const int  i  = ic * 32 + k;
        const int2 pc = *reinterpret_cast<const int2*>(&pcs[2 * i]);
        const int  xi = XC ? pc.y : pc.x;
        const int  hi = XC ? pc.x : pc.y;
        const ushort4 vx = *reinterpret_cast<const ushort4*>(GiP + (size_t)xi * 512 + d * 4);
        const ushort4 vh = *reinterpret_cast<const ushort4*>(GhP + (size_t)hi * 512 + d * 4);
        const float irs = __uint_as_float(((unsigned int)vx.x) << 16);
        const float izs = __uint_as_float(((unsigned int)vx.y) << 16);
        const float ins = __uint_as_float(((unsigned int)vx.z) << 16);
        const float hrs = __uint_as_float(((unsigned int)vh.x) << 16);
        const float hzs = __uint_as_float(((unsigned int)vh.y) << 16);
        const float hns = __uint_as_float(((unsigned int)vh.z) << 16);
        const float hv  = __uint_as_float(((unsigned int)vh.w) << 16);
        const float r = __builtin_amdgcn_rcpf(1.0f + __builtin_amdgcn_exp2f(irs + hrs));
        const float z = __builtin_amdgcn_rcpf(1.0f + __builtin_amdgcn_exp2f(izs + hzs));
        const float q = __builtin_amdgcn_rcpf(1.0f + __builtin_amdgcn_exp2f(ins + r * hns));
        const float n = 2.0f * q - 1.0f;
        acc += n + z * (hv - n);
    }
    sacc[ic][d] = acc;
    __syncthreads();

    if (ic == 0) {
        const float v   = sacc[0][d] + sacc[1][d] + sacc[2][d] + sacc[3][d];
        const int   row = 1 + bj;
        const float res = hin[(size_t)row * DD + d] + v;
        if (WRITE_OUT) {
#pragma unroll
            for (int bb = 0; bb < BB; ++bb)
                if (tgt[bb] == row) out[bb * DD + d] = res;
        } else {
            hout[(size_t)row * DD + d] = res;
        }
    } else if (ic == 1 && bj == 0 && !WRITE_OUT) {
        hout[d] = hin[d];                 // row 0 unchanged (tgt >= 1 always)
    }
}

extern "C" void kernel_launch(void* const* d_in, const int* in_sizes, int n_in,
                              void* d_out, int out_size, void* d_ws, size_t ws_size,
                              hipStream_t stream) {
    const float* hidden = (const float*)d_in[0];
    const int*   parent = (const int*)d_in[1];
    const int*   child  = (const int*)d_in[2];
    const int*   tgt    = (const int*)d_in[3];
    const float* Wif    = (const float*)d_in[4];
    const float* Whf    = (const float*)d_in[5];
    const float* bif    = (const float*)d_in[6];
    const float* bhf    = (const float*)d_in[7];
    const float* Wib    = (const float*)d_in[8];
    const float* Whb    = (const float*)d_in[9];
    const float* bib    = (const float*)d_in[10];
    const float* bhb    = (const float*)d_in[11];

    char* ws = (char*)d_ws;
    float*          WT  = (float*)(ws);                    // 4 x 128x384 f32 = 786432 B
    unsigned short* GiP = (unsigned short*)(ws + 786432);  // 1025*512 bf16 = 1049600 B
    unsigned short* GhP = (unsigned short*)(ws + 1836032); // 1025*512 bf16
    float*          h1  = (float*)(ws + 2885632);          // 1025*128 f32
    float*          out = (float*)d_out;

    const float* WibT = WT;
    const float* WhbT = WT + DD * C3;
    const float* WifT = WT + 2 * DD * C3;
    const float* WhfT = WT + 3 * DD * C3;

    wprep_kernel<<<192, 256, 0, stream>>>(Wib, Whb, Wif, Whf, WT);

    // === INSTRUMENTATION ROUND: each gtab launched 3x (idempotent; output
    // identical). dur_us ≈ base + 2*(gtab1+gtab2) -> direct attribution. ===
    gtab_kernel<<<257, 768, 0, stream>>>(hidden, WibT, WhbT, bib, bhb, GiP, GhP);
    gtab_kernel<<<257, 768, 0, stream>>>(hidden, WibT, WhbT, bib, bhb, GiP, GhP);
    gtab_kernel<<<257, 768, 0, stream>>>(hidden, WibT, WhbT, bib, bhb, GiP, GhP);
    phase_kernel<1, 0><<<BB * NN, 512, 0, stream>>>(hidden, parent, child, GiP, GhP, h1, nullptr, nullptr);
    gtab_kernel<<<257, 768, 0, stream>>>(h1, WifT, WhfT, bif, bhf, GiP, GhP);
    gtab_kernel<<<257, 768, 0, stream>>>(h1, WifT, WhfT, bif, bhf, GiP, GhP);
    gtab_kernel<<<257, 768, 0, stream>>>(h1, WifT, WhfT, bif, bhf, GiP, GhP);
    phase_kernel<0, 1><<<BB * NN, 512, 0, stream>>>(h1, parent, child, GiP, GhP, nullptr, tgt, out);
}

// Round 12
// 79.377 us; speedup vs baseline: 1.2835x; 1.2835x over previous
//
#include <hip/hip_runtime.h>
#include <hip/hip_bf16.h>

#define ROWS 1025   // B*N + 1
#define DD   128    // D
#define C3   384    // 3*D
#define BB   8
#define NN   128

#define NL2E  (-1.4426950408889634f)   // -log2(e)

__device__ __forceinline__ unsigned short f2bf(float f) {
    unsigned int i = __float_as_uint(f);            // finite data only
    return (unsigned short)((i + 0x7FFFu + ((i >> 16) & 1u)) >> 16);
}

// Transpose + pre-scale the 4 weight matrices [384][128] -> [128][384]:
//   WT[k][cc] = W[cc][k] * (cc>=256 ? 2*NL2E : NL2E)        [R9 verbatim]
__global__ __launch_bounds__(256) void wprep_kernel(
    const float* __restrict__ Wib, const float* __restrict__ Whb,
    const float* __restrict__ Wif, const float* __restrict__ Whf,
    float* __restrict__ WT) {            // 4 contiguous [128][384] tables
    const int mat = blockIdx.x / 48, tile = blockIdx.x % 48;
    const int tr = tile / 4, tc = tile % 4;      // row-tile (cc), col-tile (k)
    const float* __restrict__ src = (mat == 0) ? Wib : (mat == 1) ? Whb
                                   : (mat == 2) ? Wif : Whf;
    float* __restrict__ dst = WT + (size_t)mat * DD * C3;
    __shared__ float tl[32][33];
    const int tx = threadIdx.x & 31, ty = threadIdx.x >> 5;   // 8 rows/pass
#pragma unroll
    for (int p = 0; p < 32; p += 8) {
        const int cc = tr * 32 + ty + p, k = tc * 32 + tx;
        const float sc = (cc >= 256) ? 2.0f * NL2E : NL2E;
        tl[ty + p][tx] = src[(size_t)cc * DD + k] * sc;
    }
    __syncthreads();
#pragma unroll
    for (int p = 0; p < 32; p += 8) {
        const int k = tc * 32 + ty + p, cc = tr * 32 + tx;
        dst[(size_t)k * C3 + cc] = tl[tx][ty + p];
    }
}

// Pre-scaled packed gate tables, bf16x4 per (row, d):  [R9 verbatim]
//   GiP[row][d] = {-L*ir, -L*iz, -2L*in, (unused)}
//   GhP[row][d] = {-L*hr, -L*hz, -2L*hn, h}
__global__ __launch_bounds__(768) void gtab_kernel(
    const float* __restrict__ h,
    const float* __restrict__ WiT, const float* __restrict__ WhT,
    const float* __restrict__ bi, const float* __restrict__ bh,
    unsigned short* __restrict__ GiP, unsigned short* __restrict__ GhP) {
    __shared__ float hsT[DD][4];        // 2 KB
    const int t  = threadIdx.x;
    const int r0 = blockIdx.x * 4;
    if (t < 512) {
        const int r = t & 3, k = t >> 2;
        const int row = r0 + r;
        hsT[k][r] = (row < ROWS) ? h[(size_t)row * DD + k] : 0.0f;
    }
    __syncthreads();

    const bool isI  = t < C3;
    const int  cc   = isI ? t : t - C3;
    const int  gate = cc >> 7, d = cc & (DD - 1);
    const float* __restrict__ WT = isI ? WiT : WhT;
    const float scale = (gate == 2) ? 2.0f * NL2E : NL2E;
    const float bs = (isI ? bi : bh)[cc] * scale;   // weights pre-scaled in WT

    float a0 = 0.f, a1 = 0.f, a2 = 0.f, a3 = 0.f;
#pragma unroll 8
    for (int k = 0; k < DD; ++k) {
        const float  w  = WT[(size_t)k * C3 + cc];
        const float4 hv = *reinterpret_cast<const float4*>(&hsT[k][0]);
        a0 += w * hv.x; a1 += w * hv.y; a2 += w * hv.z; a3 += w * hv.w;
    }

    unsigned short* __restrict__ G = isI ? GiP : GhP;
    const float av[4] = {a0, a1, a2, a3};
#pragma unroll
    for (int r = 0; r < 4; ++r) {
        const int row = r0 + r;
        if (row < ROWS) G[(size_t)row * 512 + d * 4 + gate] = f2bf(av[r] + bs);
    }
    if (!isI && gate == 0) {            // h-value slot (GhP .w)
#pragma unroll
        for (int r = 0; r < 4; ++r) {
            const int row = r0 + r;
            if (row < ROWS) GhP[(size_t)row * 512 + d * 4 + 3] = f2bf(hsT[d][r]);
        }
    }
}

// One block per (b,j); 256 threads = (ic 0..1) x (d 0..127); half sums 64 i's.
// launch_bounds(256,6): VGPR cap ~84 (body ~35) -> 6-8 blocks/CU, 24-32 waves/CU.
// XC=1: x=child, h=parent (bwd). XC=0: x=parent, h=child (fwd).
template<int XC, int WRITE_OUT>
__global__ __launch_bounds__(256, 6) void phase_kernel(
    const float* __restrict__ hin,
    const int* __restrict__ parent, const int* __restrict__ child,
    const unsigned short* __restrict__ GiP, const unsigned short* __restrict__ GhP,
    float* __restrict__ hout,
    const int* __restrict__ tgt, float* __restrict__ out) {
    const int bj = blockIdx.x;          // 0..1023
    const int t  = threadIdx.x;
    const int b  = bj >> 7, j = bj & (NN - 1);
    const size_t base = (size_t)b * NN * NN + j;          // + i*NN

    __shared__ int   pcs[2 * NN];       // interleaved {p,c} pairs
    __shared__ float sacc[DD];          // ic1 partials
    if (t < NN) pcs[2 * t]              = parent[base + (size_t)t * NN];
    else        pcs[2 * (t - NN) + 1]   = child [base + (size_t)(t - NN) * NN];
    __syncthreads();

    const int ic = t >> 7, d = t & (DD - 1);
    float acc = 0.0f;
#pragma unroll 8
    for (int k = 0; k < 64; ++k) {
        const int  i  = ic * 64 + k;
        const int2 pc = *reinterpret_cast<const int2*>(&pcs[2 * i]);
        const int  xi = XC ? pc.y : pc.x;
        const int  hi = XC ? pc.x : pc.y;
        const ushort4 vx = *reinterpret_cast<const ushort4*>(GiP + (size_t)xi * 512 + d * 4);
        const ushort4 vh = *reinterpret_cast<const ushort4*>(GhP + (size_t)hi * 512 + d * 4);
        const float irs = __uint_as_float(((unsigned int)vx.x) << 16);
        const float izs = __uint_as_float(((unsigned int)vx.y) << 16);
        const float ins = __uint_as_float(((unsigned int)vx.z) << 16);
        const float hrs = __uint_as_float(((unsigned int)vh.x) << 16);
        const float hzs = __uint_as_float(((unsigned int)vh.y) << 16);
        const float hns = __uint_as_float(((unsigned int)vh.z) << 16);
        const float hv  = __uint_as_float(((unsigned int)vh.w) << 16);
        const float r = __builtin_amdgcn_rcpf(1.0f + __builtin_amdgcn_exp2f(irs + hrs));
        const float z = __builtin_amdgcn_rcpf(1.0f + __builtin_amdgcn_exp2f(izs + hzs));
        const float q = __builtin_amdgcn_rcpf(1.0f + __builtin_amdgcn_exp2f(ins + r * hns));
        const float n = 2.0f * q - 1.0f;
        acc += n + z * (hv - n);
    }
    if (ic == 1) sacc[d] = acc;
    __syncthreads();

    if (ic == 0) {
        const float v   = acc + sacc[d];
        const int   row = 1 + bj;
        const float res = hin[(size_t)row * DD + d] + v;
        if (WRITE_OUT) {
#pragma unroll
            for (int bb = 0; bb < BB; ++bb)
                if (tgt[bb] == row) out[bb * DD + d] = res;
        } else {
            hout[(size_t)row * DD + d] = res;
        }
    } else if (bj == 0 && !WRITE_OUT) {
        hout[d] = hin[d];                 // row 0 unchanged (tgt >= 1 always)
    }
}

extern "C" void kernel_launch(void* const* d_in, const int* in_sizes, int n_in,
                              void* d_out, int out_size, void* d_ws, size_t ws_size,
                              hipStream_t stream) {
    const float* hidden = (const float*)d_in[0];
    const int*   parent = (const int*)d_in[1];
    const int*   child  = (const int*)d_in[2];
    const int*   tgt    = (const int*)d_in[3];
    const float* Wif    = (const float*)d_in[4];
    const float* Whf    = (const float*)d_in[5];
    const float* bif    = (const float*)d_in[6];
    const float* bhf    = (const float*)d_in[7];
    const float* Wib    = (const float*)d_in[8];
    const float* Whb    = (const float*)d_in[9];
    const float* bib    = (const float*)d_in[10];
    const float* bhb    = (const float*)d_in[11];

    char* ws = (char*)d_ws;
    float*          WT  = (float*)(ws);                    // 4 x 128x384 f32 = 786432 B
    unsigned short* GiP = (unsigned short*)(ws + 786432);  // 1025*512 bf16 = 1049600 B
    unsigned short* GhP = (unsigned short*)(ws + 1836032); // 1025*512 bf16
    float*          h1  = (float*)(ws + 2885632);          // 1025*128 f32
    float*          out = (float*)d_out;

    const float* WibT = WT;
    const float* WhbT = WT + DD * C3;
    const float* WifT = WT + 2 * DD * C3;
    const float* WhfT = WT + 3 * DD * C3;

    wprep_kernel<<<192, 256, 0, stream>>>(Wib, Whb, Wif, Whf, WT);
    // Phase 1: bwd weights, x = child, h = parent
    gtab_kernel<<<257, 768, 0, stream>>>(hidden, WibT, WhbT, bib, bhb, GiP, GhP);
    phase_kernel<1, 0><<<BB * NN, 256, 0, stream>>>(hidden, parent, child, GiP, GhP, h1, nullptr, nullptr);
    // Phase 2: fwd weights, x = parent, h = child; tgt gather fused
    gtab_kernel<<<257, 768, 0, stream>>>(h1, WifT, WhfT, bif, bhf, GiP, GhP);
    phase_kernel<0, 1><<<BB * NN, 256, 0, stream>>>(h1, parent, child, GiP, GhP, nullptr, tgt, out);
}

// Round 13
// 67.425 us; speedup vs baseline: 1.5110x; 1.1773x over previous
//
#include <hip/hip_runtime.h>
#include <hip/hip_bf16.h>

#define ROWS 1025   // B*N + 1
#define DD   128    // D
#define C3   384    // 3*D
#define BB   8
#define NN   128

#define NL2E  (-1.4426950408889634f)   // -log2(e)

__device__ __forceinline__ unsigned short f2bf(float f) {
    unsigned int i = __float_as_uint(f);            // finite data only
    return (unsigned short)((i + 0x7FFFu + ((i >> 16) & 1u)) >> 16);
}

// Transpose + pre-scale the 4 weight matrices [384][128] -> [128][384]:
//   WT[k][cc] = W[cc][k] * (cc>=256 ? 2*NL2E : NL2E)        [R9 verbatim]
__global__ __launch_bounds__(256) void wprep_kernel(
    const float* __restrict__ Wib, const float* __restrict__ Whb,
    const float* __restrict__ Wif, const float* __restrict__ Whf,
    float* __restrict__ WT) {            // 4 contiguous [128][384] tables
    const int mat = blockIdx.x / 48, tile = blockIdx.x % 48;
    const int tr = tile / 4, tc = tile % 4;      // row-tile (cc), col-tile (k)
    const float* __restrict__ src = (mat == 0) ? Wib : (mat == 1) ? Whb
                                   : (mat == 2) ? Wif : Whf;
    float* __restrict__ dst = WT + (size_t)mat * DD * C3;
    __shared__ float tl[32][33];
    const int tx = threadIdx.x & 31, ty = threadIdx.x >> 5;   // 8 rows/pass
#pragma unroll
    for (int p = 0; p < 32; p += 8) {
        const int cc = tr * 32 + ty + p, k = tc * 32 + tx;
        const float sc = (cc >= 256) ? 2.0f * NL2E : NL2E;
        tl[ty + p][tx] = src[(size_t)cc * DD + k] * sc;
    }
    __syncthreads();
#pragma unroll
    for (int p = 0; p < 32; p += 8) {
        const int k = tc * 32 + ty + p, cc = tr * 32 + tx;
        dst[(size_t)k * C3 + cc] = tl[tx][ty + p];
    }
}

// Pre-scaled packed gate tables, bf16x4 per (row, d):  [R9 verbatim]
//   GiP[row][d] = {-L*ir, -L*iz, -2L*in, (unused)}
//   GhP[row][d] = {-L*hr, -L*hz, -2L*hn, h}
__global__ __launch_bounds__(768) void gtab_kernel(
    const float* __restrict__ h,
    const float* __restrict__ WiT, const float* __restrict__ WhT,
    const float* __restrict__ bi, const float* __restrict__ bh,
    unsigned short* __restrict__ GiP, unsigned short* __restrict__ GhP) {
    __shared__ float hsT[DD][4];        // 2 KB
    const int t  = threadIdx.x;
    const int r0 = blockIdx.x * 4;
    if (t < 512) {
        const int r = t & 3, k = t >> 2;
        const int row = r0 + r;
        hsT[k][r] = (row < ROWS) ? h[(size_t)row * DD + k] : 0.0f;
    }
    __syncthreads();

    const bool isI  = t < C3;
    const int  cc   = isI ? t : t - C3;
    const int  gate = cc >> 7, d = cc & (DD - 1);
    const float* __restrict__ WT = isI ? WiT : WhT;
    const float scale = (gate == 2) ? 2.0f * NL2E : NL2E;
    const float bs = (isI ? bi : bh)[cc] * scale;   // weights pre-scaled in WT

    float a0 = 0.f, a1 = 0.f, a2 = 0.f, a3 = 0.f;
#pragma unroll 8
    for (int k = 0; k < DD; ++k) {
        const float  w  = WT[(size_t)k * C3 + cc];
        const float4 hv = *reinterpret_cast<const float4*>(&hsT[k][0]);
        a0 += w * hv.x; a1 += w * hv.y; a2 += w * hv.z; a3 += w * hv.w;
    }

    unsigned short* __restrict__ G = isI ? GiP : GhP;
    const float av[4] = {a0, a1, a2, a3};
#pragma unroll
    for (int r = 0; r < 4; ++r) {
        const int row = r0 + r;
        if (row < ROWS) G[(size_t)row * 512 + d * 4 + gate] = f2bf(av[r] + bs);
    }
    if (!isI && gate == 0) {            // h-value slot (GhP .w)
#pragma unroll
        for (int r = 0; r < 4; ++r) {
            const int row = r0 + r;
            if (row < ROWS) GhP[(size_t)row * 512 + d * 4 + 3] = f2bf(hsT[d][r]);
        }
    }
}

// One block per (b,j); 512 threads = (ic 0..3) x (d 0..127); quarter sums 32 i's.
// Inner loop software-pipelined in chunks of 4: prefetch chunk c+1's 8 gathers
// into registers while computing chunk c (vmcnt wait lands AFTER compute).
// XC=1: x=child, h=parent (bwd). XC=0: x=parent, h=child (fwd).
template<int XC, int WRITE_OUT>
__global__ __launch_bounds__(512, 4) void phase_kernel(
    const float* __restrict__ hin,
    const int* __restrict__ parent, const int* __restrict__ child,
    const unsigned short* __restrict__ GiP, const unsigned short* __restrict__ GhP,
    float* __restrict__ hout,
    const int* __restrict__ tgt, float* __restrict__ out) {
    const int bj = blockIdx.x;          // 0..1023
    const int t  = threadIdx.x;
    const int b  = bj >> 7, j = bj & (NN - 1);
    const size_t base = (size_t)b * NN * NN + j;          // + i*NN

    __shared__ int   pcs[2 * NN];       // interleaved {p,c} pairs
    __shared__ float sacc[4][DD];
    if (t < NN)            pcs[2 * t]            = parent[base + (size_t)t * NN];
    else if (t < 2 * NN)   pcs[2 * (t - NN) + 1] = child [base + (size_t)(t - NN) * NN];
    __syncthreads();

    const int ic = t >> 7, d = t & (DD - 1);
    const int i0 = ic * 32;
    float acc = 0.0f;

    ushort4 ax0, ax1, ax2, ax3, ah0, ah1, ah2, ah3;
#define PH_LOAD(q, ii, AX, AH)                                                   \
    {                                                                            \
        const int2 pc = *reinterpret_cast<const int2*>(&pcs[2 * ((ii) + (q))]);  \
        const int  xi = XC ? pc.y : pc.x;                                        \
        const int  hi = XC ? pc.x : pc.y;                                        \
        AX = *reinterpret_cast<const ushort4*>(GiP + (size_t)xi * 512 + d * 4);  \
        AH = *reinterpret_cast<const ushort4*>(GhP + (size_t)hi * 512 + d * 4);  \
    }
#define PH_COMPUTE(VX, VH)                                                       \
    {                                                                            \
        const float irs = __uint_as_float(((unsigned int)VX.x) << 16);           \
        const float izs = __uint_as_float(((unsigned int)VX.y) << 16);           \
        const float ins = __uint_as_float(((unsigned int)VX.z) << 16);           \
        const float hrs = __uint_as_float(((unsigned int)VH.x) << 16);           \
        const float hzs = __uint_as_float(((unsigned int)VH.y) << 16);           \
        const float hns = __uint_as_float(((unsigned int)VH.z) << 16);           \
        const float hv  = __uint_as_float(((unsigned int)VH.w) << 16);           \
        const float r = __builtin_amdgcn_rcpf(1.0f + __builtin_amdgcn_exp2f(irs + hrs)); \
        const float z = __builtin_amdgcn_rcpf(1.0f + __builtin_amdgcn_exp2f(izs + hzs)); \
        const float q_ = __builtin_amdgcn_rcpf(1.0f + __builtin_amdgcn_exp2f(ins + r * hns)); \
        const float n = 2.0f * q_ - 1.0f;                                        \
        acc += n + z * (hv - n);                                                 \
    }

    PH_LOAD(0, i0, ax0, ah0)
    PH_LOAD(1, i0, ax1, ah1)
    PH_LOAD(2, i0, ax2, ah2)
    PH_LOAD(3, i0, ax3, ah3)
    for (int c0 = 0; c0 < 32; c0 += 4) {
        ushort4 bx0, bx1, bx2, bx3, bh0, bh1, bh2, bh3;
        const bool more = (c0 + 4) < 32;
        if (more) {
            const int nb = i0 + c0 + 4;
            PH_LOAD(0, nb, bx0, bh0)
            PH_LOAD(1, nb, bx1, bh1)
            PH_LOAD(2, nb, bx2, bh2)
            PH_LOAD(3, nb, bx3, bh3)
        }
        PH_COMPUTE(ax0, ah0)
        PH_COMPUTE(ax1, ah1)
        PH_COMPUTE(ax2, ah2)
        PH_COMPUTE(ax3, ah3)
        if (more) {
            ax0 = bx0; ah0 = bh0; ax1 = bx1; ah1 = bh1;
            ax2 = bx2; ah2 = bh2; ax3 = bx3; ah3 = bh3;
        }
    }
#undef PH_LOAD
#undef PH_COMPUTE

    sacc[ic][d] = acc;
    __syncthreads();

    if (ic == 0) {
        const float v   = sacc[0][d] + sacc[1][d] + sacc[2][d] + sacc[3][d];
        const int   row = 1 + bj;
        const float res = hin[(size_t)row * DD + d] + v;
        if (WRITE_OUT) {
#pragma unroll
            for (int bb = 0; bb < BB; ++bb)
                if (tgt[bb] == row) out[bb * DD + d] = res;
        } else {
            hout[(size_t)row * DD + d] = res;
        }
    } else if (ic == 1 && bj == 0 && !WRITE_OUT) {
        hout[d] = hin[d];                 // row 0 unchanged (tgt >= 1 always)
    }
}

extern "C" void kernel_launch(void* const* d_in, const int* in_sizes, int n_in,
                              void* d_out, int out_size, void* d_ws, size_t ws_size,
                              hipStream_t stream) {
    const float* hidden = (const float*)d_in[0];
    const int*   parent = (const int*)d_in[1];
    const int*   child  = (const int*)d_in[2];
    const int*   tgt    = (const int*)d_in[3];
    const float* Wif    = (const float*)d_in[4];
    const float* Whf    = (const float*)d_in[5];
    const float* bif    = (const float*)d_in[6];
    const float* bhf    = (const float*)d_in[7];
    const float* Wib    = (const float*)d_in[8];
    const float* Whb    = (const float*)d_in[9];
    const float* bib    = (const float*)d_in[10];
    const float* bhb    = (const float*)d_in[11];

    char* ws = (char*)d_ws;
    float*          WT  = (float*)(ws);                    // 4 x 128x384 f32 = 786432 B
    unsigned short* GiP = (unsigned short*)(ws + 786432);  // 1025*512 bf16 = 1049600 B
    unsigned short* GhP = (unsigned short*)(ws + 1836032); // 1025*512 bf16
    float*          h1  = (float*)(ws + 2885632);          // 1025*128 f32
    float*          out = (float*)d_out;

    const float* WibT = WT;
    const float* WhbT = WT + DD * C3;
    const float* WifT = WT + 2 * DD * C3;
    const float* WhfT = WT + 3 * DD * C3;

    wprep_kernel<<<192, 256, 0, stream>>>(Wib, Whb, Wif, Whf, WT);
    // Phase 1: bwd weights, x = child, h = parent
    gtab_kernel<<<257, 768, 0, stream>>>(hidden, WibT, WhbT, bib, bhb, GiP, GhP);
    phase_kernel<1, 0><<<BB * NN, 512, 0, stream>>>(hidden, parent, child, GiP, GhP, h1, nullptr, nullptr);
    // Phase 2: fwd weights, x = parent, h = child; tgt gather fused
    gtab_kernel<<<257, 768, 0, stream>>>(h1, WifT, WhfT, bif, bhf, GiP, GhP);
    phase_kernel<0, 1><<<BB * NN, 512, 0, stream>>>(h1, parent, child, GiP, GhP, nullptr, tgt, out);
}

// Round 14
// 63.923 us; speedup vs baseline: 1.5938x; 1.0548x over previous
//
#include <hip/hip_runtime.h>
#include <hip/hip_bf16.h>

#define ROWS 1025   // B*N + 1
#define DD   128    // D
#define C3   384    // 3*D
#define BB   8
#define NN   128

#define NL2E  (-1.4426950408889634f)   // -log2(e)

typedef __attribute__((ext_vector_type(8))) short short8x;
typedef __attribute__((ext_vector_type(4))) float float4x;

__device__ __forceinline__ unsigned short f2bf(float f) {
    unsigned int i = __float_as_uint(f);            // finite data only
    return (unsigned short)((i + 0x7FFFu + ((i >> 16) & 1u)) >> 16);
}
__device__ __forceinline__ unsigned int pk_bf16(float lo, float hi) {
    unsigned int r;
    asm("v_cvt_pk_bf16_f32 %0, %1, %2" : "=v"(r) : "v"(lo), "v"(hi));
    return r;
}

// MFMA gate-table GEMM: G[row][cc] = (dot(h[row], W[cc]) + b[cc]) * scale(gate)
// packed bf16x4 per (row,d):
//   GiP[row][d] = {-L*ir, -L*iz, -2L*in, (unused)}
//   GhP[row][d] = {-L*hr, -L*hz, -2L*hn, h}
// Grid: 65 row-tiles(16) x 4 col-groups(192) = 260 blocks, 256 thr (4 waves).
// Wave w: 3 col-tiles of 16; K=128 = 4 x mfma_f32_16x16x32_bf16.
// A (h) staged as bf16 LDS tile; B read from ORIGINAL W layout (lane = col,
// 8 contiguous k per lane -> 2x dwordx4, 16 fully-used lines/wave). No wprep.
__global__ __launch_bounds__(256) void gtab_kernel(
    const float* __restrict__ h,
    const float* __restrict__ Wi, const float* __restrict__ Wh,   // [384][128]
    const float* __restrict__ bi, const float* __restrict__ bh,
    unsigned short* __restrict__ GiP, unsigned short* __restrict__ GhP) {
    __shared__ unsigned short hsB[16][136];   // bf16 A-tile, +16B row pad
    const int t  = threadIdx.x;
    const int rt = blockIdx.x >> 2, cg = blockIdx.x & 3;
    const int r0 = rt * 16;

    // Stage h rows r0..r0+15 as bf16 (clamped; stores guarded later)
    {
        const int row  = t >> 4;               // 0..15
        const int k0   = (t & 15) * 8;         // 0..120
        const float* hp = h + (size_t)min(r0 + row, ROWS - 1) * DD + k0;
        const float4 f0 = *reinterpret_cast<const float4*>(hp);
        const float4 f1 = *reinterpret_cast<const float4*>(hp + 4);
        uint4 p;
        p.x = pk_bf16(f0.x, f0.y); p.y = pk_bf16(f0.z, f0.w);
        p.z = pk_bf16(f1.x, f1.y); p.w = pk_bf16(f1.z, f1.w);
        *reinterpret_cast<uint4*>(&hsB[row][k0]) = p;
    }
    // h-slot writes (GhP .w), once per row-tile (col-group 0 only)
    if (cg == 0) {
        for (int idx = t; idx < 16 * DD; idx += 256) {
            const int row = r0 + (idx >> 7), d = idx & (DD - 1);
            if (row < ROWS)
                GhP[(size_t)row * 512 + d * 4 + 3] = f2bf(h[(size_t)row * DD + d]);
        }
    }
    __syncthreads();

    const int wv = t >> 6, l = t & 63;
    const int lcol = l & 15, lk = l >> 4;      // col-in-tile, k-group

    short8x afrag[4];
#pragma unroll
    for (int ks = 0; ks < 4; ++ks)
        afrag[ks] = *reinterpret_cast<const short8x*>(&hsB[lcol][ks * 32 + lk * 8]);

#pragma unroll
    for (int ct = 0; ct < 3; ++ct) {
        const int  cc2 = cg * 192 + wv * 48 + ct * 16 + lcol;   // 0..767
        const bool isI = cc2 < C3;
        const int  cc  = isI ? cc2 : cc2 - C3;
        const float* __restrict__ W = isI ? Wi : Wh;
        float4x acc = {0.f, 0.f, 0.f, 0.f};
#pragma unroll
        for (int ks = 0; ks < 4; ++ks) {
            const float* wp = W + (size_t)cc * DD + ks * 32 + lk * 8;
            const float4 g0 = *reinterpret_cast<const float4*>(wp);
            const float4 g1 = *reinterpret_cast<const float4*>(wp + 4);
            union { unsigned int u[4]; short8x s; } bu;
            bu.u[0] = pk_bf16(g0.x, g0.y); bu.u[1] = pk_bf16(g0.z, g0.w);
            bu.u[2] = pk_bf16(g1.x, g1.y); bu.u[3] = pk_bf16(g1.z, g1.w);
            acc = __builtin_amdgcn_mfma_f32_16x16x32_bf16(afrag[ks], bu.s, acc, 0, 0, 0);
        }
        // Epilogue: C layout col=lane&15, row=(lane>>4)*4+reg  [m89-verified]
        const int   gate  = cc >> 7, d = cc & (DD - 1);
        const float scale = (gate == 2) ? 2.0f * NL2E : NL2E;
        const float bv    = (isI ? bi : bh)[cc];
        unsigned short* __restrict__ G = isI ? GiP : GhP;
#pragma unroll
        for (int r = 0; r < 4; ++r) {
            const int row = r0 + lk * 4 + r;
            if (row < ROWS)
                G[(size_t)row * 512 + d * 4 + gate] = f2bf((acc[r] + bv) * scale);
        }
    }
}

// One block per (b,j); 512 threads = (ic 0..3) x (d 0..127).  [R9 verbatim]
template<int XC, int WRITE_OUT>
__global__ __launch_bounds__(512, 4) void phase_kernel(
    const float* __restrict__ hin,
    const int* __restrict__ parent, const int* __restrict__ child,
    const unsigned short* __restrict__ GiP, const unsigned short* __restrict__ GhP,
    float* __restrict__ hout,
    const int* __restrict__ tgt, float* __restrict__ out) {
    const int bj = blockIdx.x;          // 0..1023
    const int t  = threadIdx.x;
    const int b  = bj >> 7, j = bj & (NN - 1);
    const size_t base = (size_t)b * NN * NN + j;          // + i*NN

    __shared__ int   pcs[2 * NN];       // interleaved {p,c} pairs
    __shared__ float sacc[4][DD];
    if (t < NN)            pcs[2 * t]            = parent[base + (size_t)t * NN];
    else if (t < 2 * NN)   pcs[2 * (t - NN) + 1] = child [base + (size_t)(t - NN) * NN];
    __syncthreads();

    const int ic = t >> 7, d = t & (DD - 1);
    float acc = 0.0f;
#pragma unroll 4
    for (int k = 0; k < 32; ++k) {
        const int  i  = ic * 32 + k;
        const int2 pc = *reinterpret_cast<const int2*>(&pcs[2 * i]);
        const int  xi = XC ? pc.y : pc.x;
        const int  hi = XC ? pc.x : pc.y;
        const ushort4 vx = *reinterpret_cast<const ushort4*>(GiP + (size_t)xi * 512 + d * 4);
        const ushort4 vh = *reinterpret_cast<const ushort4*>(GhP + (size_t)hi * 512 + d * 4);
        const float irs = __uint_as_float(((unsigned int)vx.x) << 16);
        const float izs = __uint_as_float(((unsigned int)vx.y) << 16);
        const float ins = __uint_as_float(((unsigned int)vx.z) << 16);
        const float hrs = __uint_as_float(((unsigned int)vh.x) << 16);
        const float hzs = __uint_as_float(((unsigned int)vh.y) << 16);
        const float hns = __uint_as_float(((unsigned int)vh.z) << 16);
        const float hv  = __uint_as_float(((unsigned int)vh.w) << 16);
        const float r = __builtin_amdgcn_rcpf(1.0f + __builtin_amdgcn_exp2f(irs + hrs));
        const float z = __builtin_amdgcn_rcpf(1.0f + __builtin_amdgcn_exp2f(izs + hzs));
        const float q = __builtin_amdgcn_rcpf(1.0f + __builtin_amdgcn_exp2f(ins + r * hns));
        const float n = 2.0f * q - 1.0f;
        acc += n + z * (hv - n);
    }
    sacc[ic][d] = acc;
    __syncthreads();

    if (ic == 0) {
        const float v   = sacc[0][d] + sacc[1][d] + sacc[2][d] + sacc[3][d];
        const int   row = 1 + bj;
        const float res = hin[(size_t)row * DD + d] + v;
        if (WRITE_OUT) {
#pragma unroll
            for (int bb = 0; bb < BB; ++bb)
                if (tgt[bb] == row) out[bb * DD + d] = res;
        } else {
            hout[(size_t)row * DD + d] = res;
        }
    } else if (ic == 1 && bj == 0 && !WRITE_OUT) {
        hout[d] = hin[d];                 // row 0 unchanged (tgt >= 1 always)
    }
}

extern "C" void kernel_launch(void* const* d_in, const int* in_sizes, int n_in,
                              void* d_out, int out_size, void* d_ws, size_t ws_size,
                              hipStream_t stream) {
    const float* hidden = (const float*)d_in[0];
    const int*   parent = (const int*)d_in[1];
    const int*   child  = (const int*)d_in[2];
    const int*   tgt    = (const int*)d_in[3];
    const float* Wif    = (const float*)d_in[4];
    const float* Whf    = (const float*)d_in[5];
    const float* bif    = (const float*)d_in[6];
    const float* bhf    = (const float*)d_in[7];
    const float* Wib    = (const float*)d_in[8];
    const float* Whb    = (const float*)d_in[9];
    const float* bib    = (const float*)d_in[10];
    const float* bhb    = (const float*)d_in[11];

    char* ws = (char*)d_ws;
    unsigned short* GiP = (unsigned short*)(ws);                  // 1025*512 bf16
    unsigned short* GhP = (unsigned short*)(ws + 1049600);        // 1025*512 bf16
    float*          h1  = (float*)(ws + 2099200);                 // 1025*128 f32
    float*          out = (float*)d_out;

    // Phase 1: bwd weights, x = child, h = parent
    gtab_kernel<<<260, 256, 0, stream>>>(hidden, Wib, Whb, bib, bhb, GiP, GhP);
    phase_kernel<1, 0><<<BB * NN, 512, 0, stream>>>(hidden, parent, child, GiP, GhP, h1, nullptr, nullptr);
    // Phase 2: fwd weights, x = parent, h = child; tgt gather fused
    gtab_kernel<<<260, 256, 0, stream>>>(h1, Wif, Whf, bif, bhf, GiP, GhP);
    phase_kernel<0, 1><<<BB * NN, 512, 0, stream>>>(h1, parent, child, GiP, GhP, nullptr, tgt, out);
}

// Round 15
// 61.115 us; speedup vs baseline: 1.6670x; 1.0460x over previous
//
#include <hip/hip_runtime.h>
#include <hip/hip_bf16.h>

#define ROWS 1025   // B*N + 1
#define DD   128    // D
#define C3   384    // 3*D
#define BB   8
#define NN   128

#define NL2E  (-1.4426950408889634f)   // -log2(e)

typedef __attribute__((ext_vector_type(8))) short short8x;
typedef __attribute__((ext_vector_type(4))) float float4x;

__device__ __forceinline__ unsigned short f2bf(float f) {
    unsigned int i = __float_as_uint(f);            // finite data only
    return (unsigned short)((i + 0x7FFFu + ((i >> 16) & 1u)) >> 16);
}
__device__ __forceinline__ unsigned int pk_bf16(float lo, float hi) {
    unsigned int r;
    asm("v_cvt_pk_bf16_f32 %0, %1, %2" : "=v"(r) : "v"(lo), "v"(hi));
    return r;
}

// MFMA gate-table GEMM  [R14 verbatim]
//   GiP[row][d] = {-L*ir, -L*iz, -2L*in, (unused)}
//   GhP[row][d] = {-L*hr, -L*hz, -2L*hn, h}
__global__ __launch_bounds__(256) void gtab_kernel(
    const float* __restrict__ h,
    const float* __restrict__ Wi, const float* __restrict__ Wh,   // [384][128]
    const float* __restrict__ bi, const float* __restrict__ bh,
    unsigned short* __restrict__ GiP, unsigned short* __restrict__ GhP) {
    __shared__ unsigned short hsB[16][136];   // bf16 A-tile, +16B row pad
    const int t  = threadIdx.x;
    const int rt = blockIdx.x >> 2, cg = blockIdx.x & 3;
    const int r0 = rt * 16;

    {
        const int row  = t >> 4;               // 0..15
        const int k0   = (t & 15) * 8;         // 0..120
        const float* hp = h + (size_t)min(r0 + row, ROWS - 1) * DD + k0;
        const float4 f0 = *reinterpret_cast<const float4*>(hp);
        const float4 f1 = *reinterpret_cast<const float4*>(hp + 4);
        uint4 p;
        p.x = pk_bf16(f0.x, f0.y); p.y = pk_bf16(f0.z, f0.w);
        p.z = pk_bf16(f1.x, f1.y); p.w = pk_bf16(f1.z, f1.w);
        *reinterpret_cast<uint4*>(&hsB[row][k0]) = p;
    }
    if (cg == 0) {
        for (int idx = t; idx < 16 * DD; idx += 256) {
            const int row = r0 + (idx >> 7), d = idx & (DD - 1);
            if (row < ROWS)
                GhP[(size_t)row * 512 + d * 4 + 3] = f2bf(h[(size_t)row * DD + d]);
        }
    }
    __syncthreads();

    const int wv = t >> 6, l = t & 63;
    const int lcol = l & 15, lk = l >> 4;      // col-in-tile, k-group

    short8x afrag[4];
#pragma unroll
    for (int ks = 0; ks < 4; ++ks)
        afrag[ks] = *reinterpret_cast<const short8x*>(&hsB[lcol][ks * 32 + lk * 8]);

#pragma unroll
    for (int ct = 0; ct < 3; ++ct) {
        const int  cc2 = cg * 192 + wv * 48 + ct * 16 + lcol;   // 0..767
        const bool isI = cc2 < C3;
        const int  cc  = isI ? cc2 : cc2 - C3;
        const float* __restrict__ W = isI ? Wi : Wh;
        float4x acc = {0.f, 0.f, 0.f, 0.f};
#pragma unroll
        for (int ks = 0; ks < 4; ++ks) {
            const float* wp = W + (size_t)cc * DD + ks * 32 + lk * 8;
            const float4 g0 = *reinterpret_cast<const float4*>(wp);
            const float4 g1 = *reinterpret_cast<const float4*>(wp + 4);
            union { unsigned int u[4]; short8x s; } bu;
            bu.u[0] = pk_bf16(g0.x, g0.y); bu.u[1] = pk_bf16(g0.z, g0.w);
            bu.u[2] = pk_bf16(g1.x, g1.y); bu.u[3] = pk_bf16(g1.z, g1.w);
            acc = __builtin_amdgcn_mfma_f32_16x16x32_bf16(afrag[ks], bu.s, acc, 0, 0, 0);
        }
        const int   gate  = cc >> 7, d = cc & (DD - 1);
        const float scale = (gate == 2) ? 2.0f * NL2E : NL2E;
        const float bv    = (isI ? bi : bh)[cc];
        unsigned short* __restrict__ G = isI ? GiP : GhP;
#pragma unroll
        for (int r = 0; r < 4; ++r) {
            const int row = r0 + lk * 4 + r;
            if (row < ROWS)
                G[(size_t)row * 512 + d * 4 + gate] = f2bf((acc[r] + bv) * scale);
        }
    }
}

// One block per (b,j); 512 threads = 8 waves. Lane owns a d-PAIR (16B loads):
// one wave covers all 128 d of one i per iter; wave w handles i = w + 8*it,
// it = 0..15. Halves load instrs / addr math / pcs reads / loop overhead per
// element vs the 8B-per-lane version. 8-way wave reduction at the end.
template<int XC, int WRITE_OUT>
__global__ __launch_bounds__(512, 4) void phase_kernel(
    const float* __restrict__ hin,
    const int* __restrict__ parent, const int* __restrict__ child,
    const unsigned short* __restrict__ GiP, const unsigned short* __restrict__ GhP,
    float* __restrict__ hout,
    const int* __restrict__ tgt, float* __restrict__ out) {
    const int bj = blockIdx.x;          // 0..1023
    const int t  = threadIdx.x;
    const int b  = bj >> 7, j = bj & (NN - 1);
    const size_t base = (size_t)b * NN * NN + j;          // + i*NN

    __shared__ int   pcs[2 * NN];       // interleaved {p,c} pairs
    __shared__ float sacc[8][DD];       // 4 KB
    if (t < NN)            pcs[2 * t]            = parent[base + (size_t)t * NN];
    else if (t < 2 * NN)   pcs[2 * (t - NN) + 1] = child [base + (size_t)(t - NN) * NN];
    __syncthreads();

    const int w = t >> 6, l = t & 63;
    const int d0 = l * 2;               // d-pair (d0, d0+1)
    float acc0 = 0.0f, acc1 = 0.0f;
#pragma unroll 4
    for (int it = 0; it < 16; ++it) {
        const int  i  = w + it * 8;
        const int2 pc = *reinterpret_cast<const int2*>(&pcs[2 * i]);
        const int  xi = XC ? pc.y : pc.x;
        const int  hi = XC ? pc.x : pc.y;
        const uint4 ux = *reinterpret_cast<const uint4*>(GiP + (size_t)xi * 512 + d0 * 4);
        const uint4 uh = *reinterpret_cast<const uint4*>(GhP + (size_t)hi * 512 + d0 * 4);
        // element d0
        {
            const float irs = __uint_as_float(ux.x << 16);
            const float izs = __uint_as_float(ux.x & 0xffff0000u);
            const float ins = __uint_as_float(ux.y << 16);
            const float hrs = __uint_as_float(uh.x << 16);
            const float hzs = __uint_as_float(uh.x & 0xffff0000u);
            const float hns = __uint_as_float(uh.y << 16);
            const float hv  = __uint_as_float(uh.y & 0xffff0000u);
            const float r = __builtin_amdgcn_rcpf(1.0f + __builtin_amdgcn_exp2f(irs + hrs));
            const float z = __builtin_amdgcn_rcpf(1.0f + __builtin_amdgcn_exp2f(izs + hzs));
            const float q = __builtin_amdgcn_rcpf(1.0f + __builtin_amdgcn_exp2f(ins + r * hns));
            const float n = 2.0f * q - 1.0f;
            acc0 += n + z * (hv - n);
        }
        // element d0+1
        {
            const float irs = __uint_as_float(ux.z << 16);
            const float izs = __uint_as_float(ux.z & 0xffff0000u);
            const float ins = __uint_as_float(ux.w << 16);
            const float hrs = __uint_as_float(uh.z << 16);
            const float hzs = __uint_as_float(uh.z & 0xffff0000u);
            const float hns = __uint_as_float(uh.w << 16);
            const float hv  = __uint_as_float(uh.w & 0xffff0000u);
            const float r = __builtin_amdgcn_rcpf(1.0f + __builtin_amdgcn_exp2f(irs + hrs));
            const float z = __builtin_amdgcn_rcpf(1.0f + __builtin_amdgcn_exp2f(izs + hzs));
            const float q = __builtin_amdgcn_rcpf(1.0f + __builtin_amdgcn_exp2f(ins + r * hns));
            const float n = 2.0f * q - 1.0f;
            acc1 += n + z * (hv - n);
        }
    }
    sacc[w][d0] = acc0;
    sacc[w][d0 + 1] = acc1;
    __syncthreads();

    if (t < DD) {
        const int d = t;
        float v = sacc[0][d];
#pragma unroll
        for (int ww = 1; ww < 8; ++ww) v += sacc[ww][d];
        const int   row = 1 + bj;
        const float res = hin[(size_t)row * DD + d] + v;
        if (WRITE_OUT) {
#pragma unroll
            for (int bb = 0; bb < BB; ++bb)
                if (tgt[bb] == row) out[bb * DD + d] = res;
        } else {
            hout[(size_t)row * DD + d] = res;
        }
    } else if (t < 2 * DD && bj == 0 && !WRITE_OUT) {
        hout[t - DD] = hin[t - DD];       // row 0 unchanged (tgt >= 1 always)
    }
}

extern "C" void kernel_launch(void* const* d_in, const int* in_sizes, int n_in,
                              void* d_out, int out_size, void* d_ws, size_t ws_size,
                              hipStream_t stream) {
    const float* hidden = (const float*)d_in[0];
    const int*   parent = (const int*)d_in[1];
    const int*   child  = (const int*)d_in[2];
    const int*   tgt    = (const int*)d_in[3];
    const float* Wif    = (const float*)d_in[4];
    const float* Whf    = (const float*)d_in[5];
    const float* bif    = (const float*)d_in[6];
    const float* bhf    = (const float*)d_in[7];
    const float* Wib    = (const float*)d_in[8];
    const float* Whb    = (const float*)d_in[9];
    const float* bib    = (const float*)d_in[10];
    const float* bhb    = (const float*)d_in[11];

    char* ws = (char*)d_ws;
    unsigned short* GiP = (unsigned short*)(ws);                  // 1025*512 bf16
    unsigned short* GhP = (unsigned short*)(ws + 1049600);        // 1025*512 bf16
    float*          h1  = (float*)(ws + 2099200);                 // 1025*128 f32
    float*          out = (float*)d_out;

    // Phase 1: bwd weights, x = child, h = parent
    gtab_kernel<<<260, 256, 0, stream>>>(hidden, Wib, Whb, bib, bhb, GiP, GhP);
    phase_kernel<1, 0><<<BB * NN, 512, 0, stream>>>(hidden, parent, child, GiP, GhP, h1, nullptr, nullptr);
    // Phase 2: fwd weights, x = parent, h = child; tgt gather fused
    gtab_kernel<<<260, 256, 0, stream>>>(h1, Wif, Whf, bif, bhf, GiP, GhP);
    phase_kernel<0, 1><<<BB * NN, 512, 0, stream>>>(h1, parent, child, GiP, GhP, nullptr, tgt, out);
}